// Round 12
// baseline (189.954 us; speedup 1.0000x reference)
//
#include <hip/hip_runtime.h>
#include <hip/hip_bf16.h>

#define NB 16
#define NQ 128
#define NK 512
#define DIN 256   // QS == KS == 256
#define NH 128
#define NDV 256

// tanh(x) = 1 - 2/(1+e^{2x});  e^{2x} = 2^{x*2*log2(e)}
// large +x -> exp2=inf -> rcp=0 -> 1; large -x -> exp2=0 -> 1-2 = -1. NaN-free.
__device__ __forceinline__ float fast_tanh(float x) {
    float t = __builtin_amdgcn_exp2f(x * 2.8853900817779268f);
    return 1.0f - 2.0f * __builtin_amdgcn_rcpf(t + 1.0f);
}

// P[b,r,h] = sum_d X[b,r,d] * W[d,h].  X f32 [B,R,256], W f32 [256,128], P f32.
// Block: 256 thr, 16 rows of one b. h = tid&127, rg = tid>>7 -> 8 rows each.
// W read from global (coalesced 512B/wave, L2-resident). X tile in 16KB LDS.
// Within a wave the Xl address is uniform -> LDS broadcast, conflict-free.
template<int R>
__global__ __launch_bounds__(256) void proj_kernel(
    const float* __restrict__ X,
    const float* __restrict__ W,
    float* __restrict__ P)
{
    __shared__ float Xl[16 * DIN];   // 16KB
    const int tid = threadIdx.x;
    const int tpb = R / 16;
    const int b = blockIdx.x / tpb;
    const int r0 = (blockIdx.x % tpb) * 16;

    const float4* Xg = (const float4*)(X + ((size_t)b * R + r0) * DIN);  // 1024 chunks
    float4* Xls = (float4*)Xl;
    #pragma unroll
    for (int i = 0; i < 4; ++i) Xls[tid + 256 * i] = Xg[tid + 256 * i];
    __syncthreads();

    const int h  = tid & 127;
    const int rg = tid >> 7;           // rows rg*8 .. rg*8+7
    float acc[8];
    #pragma unroll
    for (int r = 0; r < 8; ++r) acc[r] = 0.f;

    #pragma unroll 4
    for (int d = 0; d < DIN; ++d) {
        float w = W[d * NH + h];       // coalesced across lanes
        #pragma unroll
        for (int r = 0; r < 8; ++r)
            acc[r] += Xl[(rg * 8 + r) * DIN + d] * w;   // wave-uniform -> broadcast
    }
    float* Pp = P + ((size_t)b * R + r0) * NH + h;
    #pragma unroll
    for (int r = 0; r < 8; ++r) Pp[(rg * 8 + r) * NH] = acc[r];
}

// scores[b,q,k] = sum_h wv[h]*tanh(qp[b,q,h]+kp[b,k,h]); masked softmax over k fused.
// Block: 256 thr handles (b, 4 q rows, all 512 k). Grid = NB*32.
__global__ __launch_bounds__(256) void scores_softmax_kernel(
    const float* __restrict__ QP, const float* __restrict__ KP,
    const float* __restrict__ wv, const int* __restrict__ vlen,
    float* __restrict__ ATTN)
{
    __shared__ float qpl[4][NH];   // 2KB
    __shared__ float wvl[NH];      // 0.5KB
    __shared__ float sc[4][NK];    // 8KB
    const int tid = threadIdx.x;
    const int b = blockIdx.x >> 5;
    const int q0 = (blockIdx.x & 31) * 4;

    const float* qg = QP + ((size_t)b * NQ + q0) * NH;
    for (int i = tid; i < 4 * NH; i += 256) ((float*)qpl)[i] = qg[i];
    if (tid < NH) wvl[tid] = wv[tid];
    __syncthreads();

    int vl = vlen[b];
    vl = vl < 1 ? 1 : (vl > NK ? NK : vl);   // ref domain is [1, K]
    #pragma unroll
    for (int kp2 = 0; kp2 < 2; ++kp2) {
        const int k = kp2 * 256 + tid;
        const float* kr = KP + ((size_t)b * NK + k) * NH;
        float a0 = 0.f, a1 = 0.f, a2 = 0.f, a3 = 0.f;
        #pragma unroll 2
        for (int h = 0; h < NH; h += 4) {
            float4 kv = *(const float4*)(kr + h);
            float4 wq = *(const float4*)&wvl[h];
            float4 p0 = *(const float4*)&qpl[0][h];
            float4 p1 = *(const float4*)&qpl[1][h];
            float4 p2 = *(const float4*)&qpl[2][h];
            float4 p3 = *(const float4*)&qpl[3][h];
            a0 += wq.x*fast_tanh(p0.x+kv.x) + wq.y*fast_tanh(p0.y+kv.y)
                + wq.z*fast_tanh(p0.z+kv.z) + wq.w*fast_tanh(p0.w+kv.w);
            a1 += wq.x*fast_tanh(p1.x+kv.x) + wq.y*fast_tanh(p1.y+kv.y)
                + wq.z*fast_tanh(p1.z+kv.z) + wq.w*fast_tanh(p1.w+kv.w);
            a2 += wq.x*fast_tanh(p2.x+kv.x) + wq.y*fast_tanh(p2.y+kv.y)
                + wq.z*fast_tanh(p2.z+kv.z) + wq.w*fast_tanh(p2.w+kv.w);
            a3 += wq.x*fast_tanh(p3.x+kv.x) + wq.y*fast_tanh(p3.y+kv.y)
                + wq.z*fast_tanh(p3.z+kv.z) + wq.w*fast_tanh(p3.w+kv.w);
        }
        const bool valid = (k < vl);
        sc[0][k] = valid ? a0 : -1e6f;
        sc[1][k] = valid ? a1 : -1e6f;
        sc[2][k] = valid ? a2 : -1e6f;
        sc[3][k] = valid ? a3 : -1e6f;
    }
    __syncthreads();

    // one wave per q row: masked softmax over 512
    const int w = tid >> 6, lane = tid & 63;
    float vals[8];
    float m = -3.0e38f;
    #pragma unroll
    for (int i = 0; i < 8; ++i) { vals[i] = sc[w][lane + 64 * i]; m = fmaxf(m, vals[i]); }
    #pragma unroll
    for (int off = 32; off; off >>= 1) m = fmaxf(m, __shfl_xor(m, off, 64));
    float s = 0.f;
    #pragma unroll
    for (int i = 0; i < 8; ++i) {
        vals[i] = __builtin_amdgcn_exp2f((vals[i] - m) * 1.4426950408889634f);
        s += vals[i];
    }
    #pragma unroll
    for (int off = 32; off; off >>= 1) s += __shfl_xor(s, off, 64);
    const float invs = 1.0f / s;   // s >= 1 (max element contributes exp2(0)=1)
    float* ag = ATTN + ((size_t)b * NQ + q0 + w) * NK;
    #pragma unroll
    for (int i = 0; i < 8; ++i) ag[lane + 64 * i] = vals[i] * invs;
}

// out[b,q,d] = sum_k attn[b,q,k] * V[b,k,d].  V f32, OUT f32.
// Block: (b, 8 q), 256 thr: dg = tid&63 -> d = dg*4..dg*4+3 ; qg = tid>>6 -> rows {qg*2, qg*2+1}
__global__ __launch_bounds__(256) void out_kernel(
    const float* __restrict__ ATTN, const float* __restrict__ V,
    float* __restrict__ OUT)
{
    __shared__ float al[8][NK];   // 16KB
    const int tid = threadIdx.x;
    const int b = blockIdx.x >> 4;
    const int q0 = (blockIdx.x & 15) * 8;
    const float4* ag = (const float4*)(ATTN + ((size_t)b * NQ + q0) * NK);  // 1024 chunks
    float4* als = (float4*)al;
    #pragma unroll
    for (int i = 0; i < 4; ++i) als[tid + 256 * i] = ag[tid + 256 * i];
    __syncthreads();

    const int dg = tid & 63;
    const int qg = tid >> 6;
    float acc[2][4];
    #pragma unroll
    for (int j = 0; j < 2; ++j)
        #pragma unroll
        for (int i = 0; i < 4; ++i) acc[j][i] = 0.f;

    const float* vb = V + (size_t)b * NK * NDV + dg * 4;
    #pragma unroll 4
    for (int k = 0; k < NK; ++k) {
        float4 v4 = *(const float4*)(vb + (size_t)k * NDV);   // 1KB/wave coalesced
        float a0 = al[qg * 2][k], a1 = al[qg * 2 + 1][k];     // wave-uniform -> broadcast
        acc[0][0] += a0 * v4.x; acc[0][1] += a0 * v4.y; acc[0][2] += a0 * v4.z; acc[0][3] += a0 * v4.w;
        acc[1][0] += a1 * v4.x; acc[1][1] += a1 * v4.y; acc[1][2] += a1 * v4.z; acc[1][3] += a1 * v4.w;
    }
    #pragma unroll
    for (int j = 0; j < 2; ++j) {
        float4 o;
        o.x = acc[j][0]; o.y = acc[j][1]; o.z = acc[j][2]; o.w = acc[j][3];
        *(float4*)&OUT[((size_t)b * NQ + q0 + qg * 2 + j) * NDV + dg * 4] = o;
    }
}

extern "C" void kernel_launch(void* const* d_in, const int* in_sizes, int n_in,
                              void* d_out, int out_size, void* d_ws, size_t ws_size,
                              hipStream_t stream) {
    const float* queries = (const float*)d_in[0];  // [16,128,256] f32
    const float* keys    = (const float*)d_in[1];  // [16,512,256] f32
    const float* values  = (const float*)d_in[2];  // [16,512,256] f32
    const int*   vlen    = (const int*)d_in[3];    // [16] int32
    const float* Wq      = (const float*)d_in[4];  // [256,128] f32
    const float* Wk      = (const float*)d_in[5];  // [256,128] f32
    const float* wv      = (const float*)d_in[6];  // [128] f32
    float* out           = (float*)d_out;          // [16,128,256] f32

    float* qp   = (float*)d_ws;                      // 16*128*128 f32 = 1MB
    float* kp   = qp + (size_t)NB * NQ * NH;         // 16*512*128 f32 = 4MB
    float* attn = kp + (size_t)NB * NK * NH;         // 16*128*512 f32 = 4MB

    proj_kernel<NQ><<<NB * NQ / 16, 256, 0, stream>>>(queries, Wq, qp);
    proj_kernel<NK><<<NB * NK / 16, 256, 0, stream>>>(keys, Wk, kp);
    scores_softmax_kernel<<<NB * 32, 256, 0, stream>>>(qp, kp, wv, vlen, attn);
    out_kernel<<<NB * 16, 256, 0, stream>>>(attn, values, out);
}